// Round 6
// baseline (252.713 us; speedup 1.0000x reference)
//
#include <hip/hip_runtime.h>

typedef __attribute__((ext_vector_type(8))) short short8;
typedef __attribute__((ext_vector_type(4))) short short4v;
typedef __attribute__((ext_vector_type(4))) float floatx4;

__device__ inline float b2f(ushort u) {
    union { uint i; float f; } c; c.i = ((uint)u) << 16; return c.f;
}
__device__ inline ushort f2b(float f) {
    union { uint i; float f; } c; c.f = f;
    uint i = c.i;
    uint r = (i + 0x7FFFu + ((i >> 16) & 1u)) >> 16;
    return (ushort)r;
}
__device__ inline ushort f2b_fast(float f) {   // round-half-up; fine for P in [0,1]
    union { uint i; float f; } c; c.f = f;
    return (ushort)((c.i + 0x8000u) >> 16);
}

__device__ __forceinline__ void load_lds16(const ushort* g, ushort* l) {
    __builtin_amdgcn_global_load_lds((const __attribute__((address_space(1))) void*)g,
                                     (__attribute__((address_space(3))) void*)l, 16, 0, 0);
}

// Fused fp32->bf16 conversion of x, wq, wk, wv (one launch).
__global__ __launch_bounds__(256) void cvt4_k(const float* __restrict__ x,
                                              const float* __restrict__ wq,
                                              const float* __restrict__ wk,
                                              const float* __restrict__ wv,
                                              ushort* __restrict__ xb,
                                              ushort* __restrict__ wqb,
                                              ushort* __restrict__ wkb,
                                              ushort* __restrict__ wvb) {
    const int blk = blockIdx.x;
    const float* in; ushort* out; int base;
    if (blk < 2048)      { in = x;  out = xb;  base = blk; }
    else if (blk < 2560) { in = wq; out = wqb; base = blk - 2048; }
    else if (blk < 3072) { in = wk; out = wkb; base = blk - 2560; }
    else                 { in = wv; out = wvb; base = blk - 3072; }
    const int i = (base * 256 + threadIdx.x) * 8;
    float4 f0 = *(const float4*)(in + i);
    float4 f1 = *(const float4*)(in + i + 4);
    ushort u[8] = {f2b(f0.x), f2b(f0.y), f2b(f0.z), f2b(f0.w),
                   f2b(f1.x), f2b(f1.y), f2b(f1.z), f2b(f1.w)};
    *(uint4*)(out + i) = *(const uint4*)u;
}

__global__ __launch_bounds__(256) void cvt_k(const float* __restrict__ in,
                                             ushort* __restrict__ out, int n) {
    const int i = (blockIdx.x * 256 + threadIdx.x) * 8;
    if (i >= n) return;
    float4 f0 = *(const float4*)(in + i);
    float4 f1 = *(const float4*)(in + i + 4);
    ushort u[8] = {f2b(f0.x), f2b(f0.y), f2b(f0.z), f2b(f0.w),
                   f2b(f1.x), f2b(f1.y), f2b(f1.z), f2b(f1.w)};
    *(uint4*)(out + i) = *(const uint4*)u;
}

// m97-style 128x128 GEMM body, K=1024, BK=32, 4 waves (2x2 of 64x64).
// Optional fused RoPE epilogue (rows = b*2048+s, cols = h*64+d layout).
template <bool OUTF32>
__device__ __forceinline__ void gemm_body(ushort* As, ushort* Bs,
                                          const ushort* __restrict__ A,
                                          const ushort* __restrict__ B,
                                          void* __restrict__ C,
                                          int N, int m0, int n0,
                                          bool doRope, const int* __restrict__ pos) {
    const int tid = threadIdx.x;
    const int wave = tid >> 6, lane = tid & 63;
    const int quad = lane >> 4, l16 = lane & 15;
    const int wm = (wave >> 1) * 64, wn = (wave & 1) * 64;

    floatx4 acc[4][4] = {};

    const int c1 = tid, c2 = tid + 256;
    const ushort* ga1 = A + (size_t)(m0 + (c1 >> 2)) * 1024 + (c1 & 3) * 8;
    const ushort* ga2 = A + (size_t)(m0 + (c2 >> 2)) * 1024 + (c2 & 3) * 8;
    const ushort* gb1 = B + (size_t)(n0 + (c1 >> 2)) * 1024 + (c1 & 3) * 8;
    const ushort* gb2 = B + (size_t)(n0 + (c2 >> 2)) * 1024 + (c2 & 3) * 8;
    ushort* la1 = As + c1 * 8;
    ushort* la2 = As + c2 * 8;
    ushort* lb1 = Bs + c1 * 8;
    ushort* lb2 = Bs + c2 * 8;

    for (int kt = 0; kt < 32; ++kt) {
        __syncthreads();
        load_lds16(ga1 + kt * 32, la1);
        load_lds16(ga2 + kt * 32, la2);
        load_lds16(gb1 + kt * 32, lb1);
        load_lds16(gb2 + kt * 32, lb2);
        __syncthreads();
        short8 af[4], bf[4];
#pragma unroll
        for (int i = 0; i < 4; ++i) {
            af[i] = *(const short8*)(As + (wm + i * 16 + l16) * 32 + quad * 8);
            bf[i] = *(const short8*)(Bs + (wn + i * 16 + l16) * 32 + quad * 8);
        }
#pragma unroll
        for (int mi = 0; mi < 4; ++mi)
#pragma unroll
            for (int ni = 0; ni < 4; ++ni)
                acc[mi][ni] = __builtin_amdgcn_mfma_f32_16x16x32_bf16(af[mi], bf[ni], acc[mi][ni], 0, 0, 0);
    }
#pragma unroll
    for (int mi = 0; mi < 4; ++mi) {
        const int row = m0 + wm + mi * 16 + quad * 4;
#pragma unroll
        for (int ni = 0; ni < 4; ++ni) {
            const int col = n0 + wn + ni * 16 + l16;
            const int fi = (col & 63) >> 1;      // rope pair index within head
            const float inv = exp2f(-(float)fi * 0.41524101186092557f);
#pragma unroll
            for (int r = 0; r < 4; ++r) {
                float v = acc[mi][ni][r];
                if (doRope) {
                    const float other = __shfl_xor(v, 1);
                    const float p = (float)pos[(row + r) & 2047];
                    const float ang = p * inv;
                    const float sn = __sinf(ang), cs = __cosf(ang);
                    v = (col & 1) ? (other * sn + v * cs) : (v * cs - other * sn);
                }
                if (OUTF32) ((float*)C)[(size_t)(row + r) * N + col] = v;
                else        ((ushort*)C)[(size_t)(row + r) * N + col] = f2b(v);
            }
        }
    }
}

// Fused Q/K/Vt GEMM: 768 blocks (3/CU). RoPE fused for Q,K jobs.
__global__ __launch_bounds__(256) void gemm_qkv(const ushort* __restrict__ xb,
                                                const ushort* __restrict__ wqb,
                                                const ushort* __restrict__ wkb,
                                                const ushort* __restrict__ wvb,
                                                ushort* __restrict__ q,
                                                ushort* __restrict__ k,
                                                ushort* __restrict__ vt,
                                                const int* __restrict__ pos) {
    __shared__ __align__(16) ushort As[4096], Bs[4096];
    const int blk = blockIdx.x;
    const int job = blk >> 8, r = blk & 255;
    const ushort *A, *B;
    ushort* C;
    int N, m0, n0;
    bool rope;
    if (job == 0)      { A = xb;  B = wqb; C = q;  N = 1024; m0 = (r >> 3) * 128; n0 = (r & 7) * 128; rope = true; }
    else if (job == 1) { A = xb;  B = wkb; C = k;  N = 1024; m0 = (r >> 3) * 128; n0 = (r & 7) * 128; rope = true; }
    else               { A = wvb; B = xb;  C = vt; N = 4096; m0 = (r & 7) * 128;  n0 = (r >> 3) * 128; rope = false; }
    gemm_body<false>(As, Bs, A, B, C, N, m0, n0, rope, pos);
}

// Output projection: C fp32 = O[4096][1024] * wo[1024][1024]^T
__global__ __launch_bounds__(256) void gemm_o(const ushort* __restrict__ A,
                                              const ushort* __restrict__ B,
                                              float* __restrict__ C) {
    __shared__ __align__(16) ushort As[4096], Bs[4096];
    gemm_body<true>(As, Bs, A, B, C, 1024, blockIdx.y * 128, blockIdx.x * 128, false, nullptr);
}

// Causal flash attention, perfectly balanced: each block handles the q-tile
// PAIR (qt, 63-qt) of 32 rows each -> exactly 33 k-tile iterations per block,
// independent of dispatch order. 1024 blocks x 128 threads (2 waves).
// S^T = K Q^T (q=lane&15 -> per-lane softmax), P in regs, O^T = V^T P^T.
// LDS chunk-swizzle as round 5 (verified).
__global__ __launch_bounds__(128) void attn_k(const ushort* __restrict__ Qg,
                                              const ushort* __restrict__ Kg,
                                              const ushort* __restrict__ Vtg,
                                              ushort* __restrict__ Og) {
    __shared__ __align__(16) ushort Ks[2][4096];   // [s][d] swizzled
    __shared__ __align__(16) ushort Vs[2][4096];   // [d][s] swizzled

    const int tid = threadIdx.x;
    const int wave = tid >> 6, lane = tid & 63;
    const int quad = lane >> 4, l16 = lane & 15;
    const int blk = blockIdx.x;
    const int pr = blk & 31, bh = blk >> 5;
    const int b = bh >> 4, h = bh & 15;
    const int bq = b * 2048;
    const int wl = wave * 16 + l16;                // q-row within 32-row tile

    // staging: 4 chunks per array per thread (512 chunks / 128 threads)
    const ushort* kg[4];
    const ushort* vg[4];
    ushort* lk[4];
    ushort* lv[4];
    int ldsOff[4];
#pragma unroll
    for (int m = 0; m < 4; ++m) {
        const int c = tid + m * 128;
        const int s = c >> 3, j = ((c & 7) - s) & 7;
        ldsOff[m] = c * 8;
        kg[m] = Kg + (size_t)(bq + s) * 1024 + h * 64 + j * 8;
        vg[m] = Vtg + (size_t)(h * 64 + s) * 4096 + bq + j * 8;
    }

    for (int half = 0; half < 2; ++half) {
        const int qt = half ? (63 - pr) : pr;
        const int nk = (qt >> 1) + 1;
        const int dt = nk - 1;
        const int qoff = ((qt & 1) << 5) + wl;     // mask threshold (64-col tile coords)

        // Q fragments (B-operand): lane holds Q[qt*32+wl][quad*8+j]
        const ushort* qrow = Qg + (size_t)(bq + qt * 32 + wl) * 1024 + h * 64 + quad * 8;
        const short8 qf0 = *(const short8*)qrow;
        const short8 qf1 = *(const short8*)(qrow + 32);

        floatx4 od[4] = {};
        float m_st = -1e30f, l_st = 0.0f;

        // stage k-tile 0 into buffer 0
#pragma unroll
        for (int m = 0; m < 4; ++m) {
            load_lds16(kg[m], &Ks[0][ldsOff[m]]);
            load_lds16(vg[m], &Vs[0][ldsOff[m]]);
        }
        __syncthreads();

        for (int kt = 0; kt < nk; ++kt) {
            const int cur = kt & 1;
            if (kt + 1 < nk) {
                const int nxt = cur ^ 1;
#pragma unroll
                for (int m = 0; m < 4; ++m) {
                    load_lds16(kg[m] + (size_t)(kt + 1) * 65536, &Ks[nxt][ldsOff[m]]);
                    load_lds16(vg[m] + (kt + 1) * 64, &Vs[nxt][ldsOff[m]]);
                }
            }
            const ushort* kb = Ks[cur];
            const ushort* vb = Vs[cur];

            // S^T = K Q^T
            floatx4 st[4];
#pragma unroll
            for (int cb = 0; cb < 4; ++cb) {
                const int s = cb * 16 + l16;
                const int ch0 = s * 8 + ((quad + s) & 7);
                const int ch1 = s * 8 + ((quad + 4 + s) & 7);
                short8 kf0 = *(const short8*)(kb + ch0 * 8);
                short8 kf1 = *(const short8*)(kb + ch1 * 8);
                floatx4 z = {};
                z = __builtin_amdgcn_mfma_f32_16x16x32_bf16(kf0, qf0, z, 0, 0, 0);
                z = __builtin_amdgcn_mfma_f32_16x16x32_bf16(kf1, qf1, z, 0, 0, 0);
                st[cb] = z;
            }

            // per-lane softmax (q = l16), 2 shuffles across quad replicas
            const bool diag = (kt == dt);
            float pv[4][4];
            float mx = -1e30f;
#pragma unroll
            for (int cb = 0; cb < 4; ++cb) {
                const int scb = cb * 16 + quad * 4;
#pragma unroll
                for (int r = 0; r < 4; ++r) {
                    float v = st[cb][r] * 0.125f;
                    if (diag && (scb + r > qoff)) v = -1e30f;
                    pv[cb][r] = v;
                    mx = fmaxf(mx, v);
                }
            }
            mx = fmaxf(mx, __shfl_xor(mx, 16));
            mx = fmaxf(mx, __shfl_xor(mx, 32));
            const float mn = fmaxf(m_st, mx);
            const float alpha = __expf(m_st - mn);
            m_st = mn;
            float sum = 0.0f;
#pragma unroll
            for (int cb = 0; cb < 4; ++cb)
#pragma unroll
                for (int r = 0; r < 4; ++r) {
                    const float p = __expf(pv[cb][r] - mn);
                    pv[cb][r] = p;
                    sum += p;
                }
            sum += __shfl_xor(sum, 16);
            sum += __shfl_xor(sum, 32);
            l_st = l_st * alpha + sum;

            // P^T fragments (B-operand of 16x16x16) straight from registers
            short4v pb[4];
#pragma unroll
            for (int cb = 0; cb < 4; ++cb) {
                short4v pk;
#pragma unroll
                for (int r = 0; r < 4; ++r) pk[r] = (short)f2b_fast(pv[cb][r]);
                pb[cb] = pk;
            }
            // O^T += V^T P^T
#pragma unroll
            for (int db = 0; db < 4; ++db) {
                od[db] *= alpha;
                const int d = db * 16 + l16;
#pragma unroll
                for (int cb = 0; cb < 4; ++cb) {
                    const int j = cb * 2 + (quad >> 1);
                    const int ch = d * 8 + ((j + d) & 7);
                    short4v vf = *(const short4v*)(vb + ch * 8 + (quad & 1) * 4);
                    od[db] = __builtin_amdgcn_mfma_f32_16x16x16bf16_1k(vf, pb[cb], od[db], 0, 0, 0);
                }
            }
            __syncthreads();   // prefetch drained + cur reads done
        }

        const float linv = 1.0f / l_st;
        ushort* orow = Og + (size_t)(bq + qt * 32 + wl) * 1024 + h * 64 + quad * 4;
#pragma unroll
        for (int db = 0; db < 4; ++db) {
            uint2 w;
            w.x = (uint)f2b(od[db][0] * linv) | ((uint)f2b(od[db][1] * linv) << 16);
            w.y = (uint)f2b(od[db][2] * linv) | ((uint)f2b(od[db][3] * linv) << 16);
            *(uint2*)(orow + db * 16) = w;
        }
    }
}

extern "C" void kernel_launch(void* const* d_in, const int* in_sizes, int n_in,
                              void* d_out, int out_size, void* d_ws, size_t ws_size,
                              hipStream_t stream) {
    const float* x  = (const float*)d_in[0];
    const float* wq = (const float*)d_in[1];
    const float* wk = (const float*)d_in[2];
    const float* wv = (const float*)d_in[3];
    const float* wo = (const float*)d_in[4];
    const int* pos  = (const int*)d_in[5];

    const size_t NX = (size_t)4096 * 1024;
    const size_t NW = (size_t)1024 * 1024;

    ushort* q_ws  = (ushort*)d_ws;          // 8 MB each, 32 MiB total
    ushort* k_ws  = q_ws + NX;
    ushort* vt_ws = k_ws + NX;
    ushort* o_ws  = vt_ws + NX;
    // d_out doubles as bf16 scratch until the final GEMM
    ushort* xb  = (ushort*)d_out;
    ushort* wqb = xb + NX;
    ushort* wkb = wqb + NW;
    ushort* wvb = wkb + NW;

    cvt4_k<<<dim3(3584), 256, 0, stream>>>(x, wq, wk, wv, xb, wqb, wkb, wvb);
    gemm_qkv<<<dim3(768), 256, 0, stream>>>(xb, wqb, wkb, wvb, q_ws, k_ws, vt_ws, pos);
    attn_k<<<dim3(1024), 128, 0, stream>>>(q_ws, k_ws, vt_ws, o_ws);
    cvt_k<<<dim3(512), 256, 0, stream>>>(wo, q_ws, (int)NW);   // q_ws dead now
    gemm_o<<<dim3(8, 32), 256, 0, stream>>>(o_ws, q_ws, (float*)d_out);
}

// Round 7
// 229.399 us; speedup vs baseline: 1.1016x; 1.1016x over previous
//
#include <hip/hip_runtime.h>

typedef __attribute__((ext_vector_type(8))) short short8;
typedef __attribute__((ext_vector_type(4))) short short4v;
typedef __attribute__((ext_vector_type(4))) float floatx4;

__device__ inline float b2f(ushort u) {
    union { uint i; float f; } c; c.i = ((uint)u) << 16; return c.f;
}
__device__ inline ushort f2b(float f) {
    union { uint i; float f; } c; c.f = f;
    uint i = c.i;
    uint r = (i + 0x7FFFu + ((i >> 16) & 1u)) >> 16;
    return (ushort)r;
}
__device__ inline ushort f2b_fast(float f) {   // round-half-up; fine for P in [0,1]
    union { uint i; float f; } c; c.f = f;
    return (ushort)((c.i + 0x8000u) >> 16);
}

__device__ __forceinline__ void load_lds16(const ushort* g, ushort* l) {
    __builtin_amdgcn_global_load_lds((const __attribute__((address_space(1))) void*)g,
                                     (__attribute__((address_space(3))) void*)l, 16, 0, 0);
}

// RoPE cos/sin table: tab[s][fi] = {cos, sin}(pos[s] * theta^(-fi/32)), 2048x32.
__global__ __launch_bounds__(256) void rope_tab_k(const int* __restrict__ pos,
                                                  float2* __restrict__ tab) {
    const int idx = blockIdx.x * 256 + threadIdx.x;   // 0..65535
    const int s = idx >> 5, fi = idx & 31;
    const float inv = exp2f(-(float)fi * 0.41524101186092557f);
    const float ang = (float)pos[s] * inv;
    float sn, cs;
    sincosf(ang, &sn, &cs);
    tab[idx] = make_float2(cs, sn);
}

// Fused fp32->bf16 conversion of x, wq, wk, wv (one launch).
__global__ __launch_bounds__(256) void cvt4_k(const float* __restrict__ x,
                                              const float* __restrict__ wq,
                                              const float* __restrict__ wk,
                                              const float* __restrict__ wv,
                                              ushort* __restrict__ xb,
                                              ushort* __restrict__ wqb,
                                              ushort* __restrict__ wkb,
                                              ushort* __restrict__ wvb) {
    const int blk = blockIdx.x;
    const float* in; ushort* out; int base;
    if (blk < 2048)      { in = x;  out = xb;  base = blk; }
    else if (blk < 2560) { in = wq; out = wqb; base = blk - 2048; }
    else if (blk < 3072) { in = wk; out = wkb; base = blk - 2560; }
    else                 { in = wv; out = wvb; base = blk - 3072; }
    const int i = (base * 256 + threadIdx.x) * 8;
    float4 f0 = *(const float4*)(in + i);
    float4 f1 = *(const float4*)(in + i + 4);
    ushort u[8] = {f2b(f0.x), f2b(f0.y), f2b(f0.z), f2b(f0.w),
                   f2b(f1.x), f2b(f1.y), f2b(f1.z), f2b(f1.w)};
    *(uint4*)(out + i) = *(const uint4*)u;
}

__global__ __launch_bounds__(256) void cvt_k(const float* __restrict__ in,
                                             ushort* __restrict__ out, int n) {
    const int i = (blockIdx.x * 256 + threadIdx.x) * 8;
    if (i >= n) return;
    float4 f0 = *(const float4*)(in + i);
    float4 f1 = *(const float4*)(in + i + 4);
    ushort u[8] = {f2b(f0.x), f2b(f0.y), f2b(f0.z), f2b(f0.w),
                   f2b(f1.x), f2b(f1.y), f2b(f1.z), f2b(f1.w)};
    *(uint4*)(out + i) = *(const uint4*)u;
}

// m97-style 128x128 GEMM body, K=1024, BK=32, 4 waves (2x2 of 64x64).
// Optional fused RoPE epilogue via precomputed table (no transcendentals).
template <bool OUTF32>
__device__ __forceinline__ void gemm_body(ushort* As, ushort* Bs,
                                          const ushort* __restrict__ A,
                                          const ushort* __restrict__ B,
                                          void* __restrict__ C,
                                          int N, int m0, int n0,
                                          bool doRope, const float2* __restrict__ tab) {
    const int tid = threadIdx.x;
    const int wave = tid >> 6, lane = tid & 63;
    const int quad = lane >> 4, l16 = lane & 15;
    const int wm = (wave >> 1) * 64, wn = (wave & 1) * 64;

    floatx4 acc[4][4] = {};

    const int c1 = tid, c2 = tid + 256;
    const ushort* ga1 = A + (size_t)(m0 + (c1 >> 2)) * 1024 + (c1 & 3) * 8;
    const ushort* ga2 = A + (size_t)(m0 + (c2 >> 2)) * 1024 + (c2 & 3) * 8;
    const ushort* gb1 = B + (size_t)(n0 + (c1 >> 2)) * 1024 + (c1 & 3) * 8;
    const ushort* gb2 = B + (size_t)(n0 + (c2 >> 2)) * 1024 + (c2 & 3) * 8;
    ushort* la1 = As + c1 * 8;
    ushort* la2 = As + c2 * 8;
    ushort* lb1 = Bs + c1 * 8;
    ushort* lb2 = Bs + c2 * 8;

    for (int kt = 0; kt < 32; ++kt) {
        __syncthreads();
        load_lds16(ga1 + kt * 32, la1);
        load_lds16(ga2 + kt * 32, la2);
        load_lds16(gb1 + kt * 32, lb1);
        load_lds16(gb2 + kt * 32, lb2);
        __syncthreads();
        short8 af[4], bf[4];
#pragma unroll
        for (int i = 0; i < 4; ++i) {
            af[i] = *(const short8*)(As + (wm + i * 16 + l16) * 32 + quad * 8);
            bf[i] = *(const short8*)(Bs + (wn + i * 16 + l16) * 32 + quad * 8);
        }
#pragma unroll
        for (int mi = 0; mi < 4; ++mi)
#pragma unroll
            for (int ni = 0; ni < 4; ++ni)
                acc[mi][ni] = __builtin_amdgcn_mfma_f32_16x16x32_bf16(af[mi], bf[ni], acc[mi][ni], 0, 0, 0);
    }
#pragma unroll
    for (int mi = 0; mi < 4; ++mi) {
        const int row = m0 + wm + mi * 16 + quad * 4;
#pragma unroll
        for (int ni = 0; ni < 4; ++ni) {
            const int col = n0 + wn + ni * 16 + l16;
            const int fi = ((wn + ni * 16 + l16) & 63) >> 1;
#pragma unroll
            for (int r = 0; r < 4; ++r) {
                float v = acc[mi][ni][r];
                if (doRope) {
                    const float other = __shfl_xor(v, 1);
                    const float2 cs = tab[((row + r) & 2047) * 32 + fi];
                    v = (col & 1) ? (other * cs.y + v * cs.x) : (v * cs.x - other * cs.y);
                }
                if (OUTF32) ((float*)C)[(size_t)(row + r) * N + col] = v;
                else        ((ushort*)C)[(size_t)(row + r) * N + col] = f2b(v);
            }
        }
    }
}

// Fused Q/K/Vt GEMM: 768 blocks (3/CU). RoPE fused (table) for Q,K jobs.
__global__ __launch_bounds__(256) void gemm_qkv(const ushort* __restrict__ xb,
                                                const ushort* __restrict__ wqb,
                                                const ushort* __restrict__ wkb,
                                                const ushort* __restrict__ wvb,
                                                ushort* __restrict__ q,
                                                ushort* __restrict__ k,
                                                ushort* __restrict__ vt,
                                                const float2* __restrict__ tab) {
    __shared__ __align__(16) ushort As[4096], Bs[4096];
    const int blk = blockIdx.x;
    const int job = blk >> 8, r = blk & 255;
    const ushort *A, *B;
    ushort* C;
    int N, m0, n0;
    bool rope;
    if (job == 0)      { A = xb;  B = wqb; C = q;  N = 1024; m0 = (r >> 3) * 128; n0 = (r & 7) * 128; rope = true; }
    else if (job == 1) { A = xb;  B = wkb; C = k;  N = 1024; m0 = (r >> 3) * 128; n0 = (r & 7) * 128; rope = true; }
    else               { A = wvb; B = xb;  C = vt; N = 4096; m0 = (r & 7) * 128;  n0 = (r >> 3) * 128; rope = false; }
    gemm_body<false>(As, Bs, A, B, C, N, m0, n0, rope, tab);
}

// Output projection: C fp32 = O[4096][1024] * wo[1024][1024]^T
__global__ __launch_bounds__(256) void gemm_o(const ushort* __restrict__ A,
                                              const ushort* __restrict__ B,
                                              float* __restrict__ C) {
    __shared__ __align__(16) ushort As[4096], Bs[4096];
    gemm_body<true>(As, Bs, A, B, C, 1024, blockIdx.y * 128, blockIdx.x * 128, false, nullptr);
}

// Causal flash attention. 512 blocks x 256 threads (4 waves, wave w = q-rows
// w*16..w*16+15 of a 64-row q-tile). Each block runs halves (qt=pr, 31-pr):
// exactly 33 k-tile iterations per block regardless of dispatch order.
// bh = blk&31 -> blk%8 = bh%8: all blocks of one bh stay on one XCD (L2 reuse).
// S^T = K Q^T (q=lane&15 -> per-lane softmax), P in regs, O^T = V^T P^T.
__global__ __launch_bounds__(256) void attn_k(const ushort* __restrict__ Qg,
                                              const ushort* __restrict__ Kg,
                                              const ushort* __restrict__ Vtg,
                                              ushort* __restrict__ Og) {
    __shared__ __align__(16) ushort Ks[2][4096];   // [s][d] chunk-swizzled
    __shared__ __align__(16) ushort Vs[2][4096];   // [d][s] chunk-swizzled

    const int tid = threadIdx.x;
    const int wave = tid >> 6, lane = tid & 63;
    const int quad = lane >> 4, l16 = lane & 15;
    const int blk = blockIdx.x;
    const int bh = blk & 31, pr = blk >> 5;        // pr in 0..15
    const int b = bh >> 4, h = bh & 15;
    const int bq = b * 2048;
    const int wl = wave * 16 + l16;                // q-row within 64-row tile

    // staging: 2 chunks per array per thread (512 chunks / 256 threads)
    const int cA = tid, cB = tid + 256;
    const int sA = cA >> 3, jA = ((cA & 7) - sA) & 7;
    const int sB = cB >> 3, jB = ((cB & 7) - sB) & 7;
    const ushort* kgA = Kg + (size_t)(bq + sA) * 1024 + h * 64 + jA * 8;
    const ushort* kgB = Kg + (size_t)(bq + sB) * 1024 + h * 64 + jB * 8;
    const ushort* vgA = Vtg + (size_t)(h * 64 + sA) * 4096 + bq + jA * 8;
    const ushort* vgB = Vtg + (size_t)(h * 64 + sB) * 4096 + bq + jB * 8;

    for (int half = 0; half < 2; ++half) {
        const int qt = half ? (31 - pr) : pr;      // 64-row q-tile index
        const int nk = qt + 1;
        const int dt = nk - 1;

        // Q fragments (B-operand): lane holds Q[qt*64+wl][quad*8+j]
        const ushort* qrow = Qg + (size_t)(bq + qt * 64 + wl) * 1024 + h * 64 + quad * 8;
        const short8 qf0 = *(const short8*)qrow;
        const short8 qf1 = *(const short8*)(qrow + 32);

        floatx4 od[4] = {};
        float m_st = -1e30f, l_st = 0.0f;

        // stage k-tile 0 into buffer 0
        load_lds16(kgA, &Ks[0][cA * 8]);
        load_lds16(kgB, &Ks[0][cB * 8]);
        load_lds16(vgA, &Vs[0][cA * 8]);
        load_lds16(vgB, &Vs[0][cB * 8]);
        __syncthreads();

        for (int kt = 0; kt < nk; ++kt) {
            const int cur = kt & 1;
            if (kt + 1 < nk) {
                const int nxt = cur ^ 1;
                load_lds16(kgA + (size_t)(kt + 1) * 65536, &Ks[nxt][cA * 8]);
                load_lds16(kgB + (size_t)(kt + 1) * 65536, &Ks[nxt][cB * 8]);
                load_lds16(vgA + (kt + 1) * 64, &Vs[nxt][cA * 8]);
                load_lds16(vgB + (kt + 1) * 64, &Vs[nxt][cB * 8]);
            }
            const ushort* kb = Ks[cur];
            const ushort* vb = Vs[cur];

            // S^T = K Q^T
            floatx4 st[4];
#pragma unroll
            for (int cb = 0; cb < 4; ++cb) {
                const int s = cb * 16 + l16;
                const int ch0 = s * 8 + ((quad + s) & 7);
                const int ch1 = s * 8 + ((quad + 4 + s) & 7);
                short8 kf0 = *(const short8*)(kb + ch0 * 8);
                short8 kf1 = *(const short8*)(kb + ch1 * 8);
                floatx4 z = {};
                z = __builtin_amdgcn_mfma_f32_16x16x32_bf16(kf0, qf0, z, 0, 0, 0);
                z = __builtin_amdgcn_mfma_f32_16x16x32_bf16(kf1, qf1, z, 0, 0, 0);
                st[cb] = z;
            }

            // per-lane softmax (q = l16), 2 shuffles across quad replicas
            const bool diag = (kt == dt);
            float pv[4][4];
            float mx = -1e30f;
#pragma unroll
            for (int cb = 0; cb < 4; ++cb) {
                const int scb = cb * 16 + quad * 4;
#pragma unroll
                for (int r = 0; r < 4; ++r) {
                    float v = st[cb][r] * 0.125f;
                    if (diag && (scb + r > wl)) v = -1e30f;
                    pv[cb][r] = v;
                    mx = fmaxf(mx, v);
                }
            }
            mx = fmaxf(mx, __shfl_xor(mx, 16));
            mx = fmaxf(mx, __shfl_xor(mx, 32));
            const float mn = fmaxf(m_st, mx);
            const float alpha = __expf(m_st - mn);
            m_st = mn;
            float sum = 0.0f;
#pragma unroll
            for (int cb = 0; cb < 4; ++cb)
#pragma unroll
                for (int r = 0; r < 4; ++r) {
                    const float p = __expf(pv[cb][r] - mn);
                    pv[cb][r] = p;
                    sum += p;
                }
            sum += __shfl_xor(sum, 16);
            sum += __shfl_xor(sum, 32);
            l_st = l_st * alpha + sum;

            // P^T fragments (B-operand of 16x16x16) straight from registers
            short4v pb[4];
#pragma unroll
            for (int cb = 0; cb < 4; ++cb) {
                short4v pk;
#pragma unroll
                for (int r = 0; r < 4; ++r) pk[r] = (short)f2b_fast(pv[cb][r]);
                pb[cb] = pk;
            }
            // O^T += V^T P^T
#pragma unroll
            for (int db = 0; db < 4; ++db) {
                od[db] *= alpha;
                const int d = db * 16 + l16;
#pragma unroll
                for (int cb = 0; cb < 4; ++cb) {
                    const int j = cb * 2 + (quad >> 1);
                    const int ch = d * 8 + ((j + d) & 7);
                    short4v vf = *(const short4v*)(vb + ch * 8 + (quad & 1) * 4);
                    od[db] = __builtin_amdgcn_mfma_f32_16x16x16bf16_1k(vf, pb[cb], od[db], 0, 0, 0);
                }
            }
            __syncthreads();   // cur reads done + prefetch drained
        }

        const float linv = 1.0f / l_st;
        ushort* orow = Og + (size_t)(bq + qt * 64 + wl) * 1024 + h * 64 + quad * 4;
#pragma unroll
        for (int db = 0; db < 4; ++db) {
            uint2 w;
            w.x = (uint)f2b(od[db][0] * linv) | ((uint)f2b(od[db][1] * linv) << 16);
            w.y = (uint)f2b(od[db][2] * linv) | ((uint)f2b(od[db][3] * linv) << 16);
            *(uint2*)(orow + db * 16) = w;
        }
    }
}

extern "C" void kernel_launch(void* const* d_in, const int* in_sizes, int n_in,
                              void* d_out, int out_size, void* d_ws, size_t ws_size,
                              hipStream_t stream) {
    const float* x  = (const float*)d_in[0];
    const float* wq = (const float*)d_in[1];
    const float* wk = (const float*)d_in[2];
    const float* wv = (const float*)d_in[3];
    const float* wo = (const float*)d_in[4];
    const int* pos  = (const int*)d_in[5];

    const size_t NX = (size_t)4096 * 1024;
    const size_t NW = (size_t)1024 * 1024;

    ushort* q_ws  = (ushort*)d_ws;          // 8 MB each, 32 MiB total
    ushort* k_ws  = q_ws + NX;
    ushort* vt_ws = k_ws + NX;
    ushort* o_ws  = vt_ws + NX;
    // d_out (16 MB) doubles as bf16 scratch + rope table until the final GEMM
    ushort* xb  = (ushort*)d_out;           // 8 MB
    ushort* wqb = xb + NX;                  // 2 MB each
    ushort* wkb = wqb + NW;
    ushort* wvb = wkb + NW;
    float2* tab = (float2*)(wvb + NW);      // 512 KB (14 MB..14.5 MB)

    rope_tab_k<<<dim3(256), 256, 0, stream>>>(pos, tab);
    cvt4_k<<<dim3(3584), 256, 0, stream>>>(x, wq, wk, wv, xb, wqb, wkb, wvb);
    gemm_qkv<<<dim3(768), 256, 0, stream>>>(xb, wqb, wkb, wvb, q_ws, k_ws, vt_ws, tab);
    attn_k<<<dim3(512), 256, 0, stream>>>(q_ws, k_ws, vt_ws, o_ws);
    cvt_k<<<dim3(512), 256, 0, stream>>>(wo, q_ws, (int)NW);   // q_ws dead now
    gemm_o<<<dim3(8, 32), 256, 0, stream>>>(o_ws, q_ws, (float*)d_out);
}

// Round 8
// 214.704 us; speedup vs baseline: 1.1770x; 1.0684x over previous
//
#include <hip/hip_runtime.h>

typedef __attribute__((ext_vector_type(8))) short short8;
typedef __attribute__((ext_vector_type(4))) short short4v;
typedef __attribute__((ext_vector_type(4))) float floatx4;

__device__ inline float b2f(ushort u) {
    union { uint i; float f; } c; c.i = ((uint)u) << 16; return c.f;
}
__device__ inline ushort f2b(float f) {
    union { uint i; float f; } c; c.f = f;
    uint i = c.i;
    uint r = (i + 0x7FFFu + ((i >> 16) & 1u)) >> 16;
    return (ushort)r;
}
__device__ inline ushort f2b_fast(float f) {   // round-half-up; fine for P >= 0
    union { uint i; float f; } c; c.f = f;
    return (ushort)((c.i + 0x8000u) >> 16);
}

__device__ __forceinline__ void load_lds16(const ushort* g, ushort* l) {
    __builtin_amdgcn_global_load_lds((const __attribute__((address_space(1))) void*)g,
                                     (__attribute__((address_space(3))) void*)l, 16, 0, 0);
}

// RoPE cos/sin table: tab[s][fi] = {cos, sin}(pos[s] * theta^(-fi/32)), 2048x32.
__global__ __launch_bounds__(256) void rope_tab_k(const int* __restrict__ pos,
                                                  float2* __restrict__ tab) {
    const int idx = blockIdx.x * 256 + threadIdx.x;   // 0..65535
    const int s = idx >> 5, fi = idx & 31;
    const float inv = exp2f(-(float)fi * 0.41524101186092557f);
    const float ang = (float)pos[s] * inv;
    float sn, cs;
    sincosf(ang, &sn, &cs);
    tab[idx] = make_float2(cs, sn);
}

// Fused fp32->bf16 conversion of x, wq, wk, wv (one launch).
__global__ __launch_bounds__(256) void cvt4_k(const float* __restrict__ x,
                                              const float* __restrict__ wq,
                                              const float* __restrict__ wk,
                                              const float* __restrict__ wv,
                                              ushort* __restrict__ xb,
                                              ushort* __restrict__ wqb,
                                              ushort* __restrict__ wkb,
                                              ushort* __restrict__ wvb) {
    const int blk = blockIdx.x;
    const float* in; ushort* out; int base;
    if (blk < 2048)      { in = x;  out = xb;  base = blk; }
    else if (blk < 2560) { in = wq; out = wqb; base = blk - 2048; }
    else if (blk < 3072) { in = wk; out = wkb; base = blk - 2560; }
    else                 { in = wv; out = wvb; base = blk - 3072; }
    const int i = (base * 256 + threadIdx.x) * 8;
    float4 f0 = *(const float4*)(in + i);
    float4 f1 = *(const float4*)(in + i + 4);
    ushort u[8] = {f2b(f0.x), f2b(f0.y), f2b(f0.z), f2b(f0.w),
                   f2b(f1.x), f2b(f1.y), f2b(f1.z), f2b(f1.w)};
    *(uint4*)(out + i) = *(const uint4*)u;
}

__global__ __launch_bounds__(256) void cvt_k(const float* __restrict__ in,
                                             ushort* __restrict__ out, int n) {
    const int i = (blockIdx.x * 256 + threadIdx.x) * 8;
    if (i >= n) return;
    float4 f0 = *(const float4*)(in + i);
    float4 f1 = *(const float4*)(in + i + 4);
    ushort u[8] = {f2b(f0.x), f2b(f0.y), f2b(f0.z), f2b(f0.w),
                   f2b(f1.x), f2b(f1.y), f2b(f1.z), f2b(f1.w)};
    *(uint4*)(out + i) = *(const uint4*)u;
}

// 128x128 GEMM body, K=1024, BK=64, 4 waves (2x2 of 64x64).
// LDS tiles 128 rows x 64 cols (16 KB each), chunk-XOR-swizzled:
// global chunk (row, j) lives at LDS chunk row*8 + (j ^ (row&7)).
// Row stride 128B == 0 mod 32 banks -> swizzled ds_read_b128 is conflict-free.
// Optional fused RoPE epilogue via precomputed table.
template <bool OUTF32>
__device__ __forceinline__ void gemm_body(ushort* As, ushort* Bs,
                                          const ushort* __restrict__ A,
                                          const ushort* __restrict__ B,
                                          void* __restrict__ C,
                                          int N, int m0, int n0,
                                          bool doRope, const float2* __restrict__ tab) {
    const int tid = threadIdx.x;
    const int wave = tid >> 6, lane = tid & 63;
    const int quad = lane >> 4, l16 = lane & 15;
    const int wm = (wave >> 1) * 64, wn = (wave & 1) * 64;

    floatx4 acc[4][4] = {};

    // staging: 1024 chunks per tile, 4 per thread per array
    const ushort* ga[4];
    const ushort* gb[4];
    int lofs[4];
#pragma unroll
    for (int m = 0; m < 4; ++m) {
        const int c = tid + m * 256;
        const int row = c >> 3;
        const int jg = (c & 7) ^ (row & 7);
        lofs[m] = c * 8;
        ga[m] = A + (size_t)(m0 + row) * 1024 + jg * 8;
        gb[m] = B + (size_t)(n0 + row) * 1024 + jg * 8;
    }

    for (int kt = 0; kt < 16; ++kt) {
        __syncthreads();
#pragma unroll
        for (int m = 0; m < 4; ++m) {
            load_lds16(ga[m] + kt * 64, As + lofs[m]);
            load_lds16(gb[m] + kt * 64, Bs + lofs[m]);
        }
        __syncthreads();
#pragma unroll
        for (int half = 0; half < 2; ++half) {
            short8 af[4], bf[4];
            const int j = half * 4 + quad;
#pragma unroll
            for (int i = 0; i < 4; ++i) {
                const int ra = wm + i * 16 + l16;
                const int rb = wn + i * 16 + l16;
                af[i] = *(const short8*)(As + ra * 64 + (j ^ (ra & 7)) * 8);
                bf[i] = *(const short8*)(Bs + rb * 64 + (j ^ (rb & 7)) * 8);
            }
#pragma unroll
            for (int mi = 0; mi < 4; ++mi)
#pragma unroll
                for (int ni = 0; ni < 4; ++ni)
                    acc[mi][ni] = __builtin_amdgcn_mfma_f32_16x16x32_bf16(af[mi], bf[ni], acc[mi][ni], 0, 0, 0);
        }
    }
#pragma unroll
    for (int mi = 0; mi < 4; ++mi) {
        const int row = m0 + wm + mi * 16 + quad * 4;
#pragma unroll
        for (int ni = 0; ni < 4; ++ni) {
            const int col = n0 + wn + ni * 16 + l16;
            const int fi = ((wn + ni * 16 + l16) & 63) >> 1;
#pragma unroll
            for (int r = 0; r < 4; ++r) {
                float v = acc[mi][ni][r];
                if (doRope) {
                    const float other = __shfl_xor(v, 1);
                    const float2 cs = tab[((row + r) & 2047) * 32 + fi];
                    v = (col & 1) ? (other * cs.y + v * cs.x) : (v * cs.x - other * cs.y);
                }
                if (OUTF32) ((float*)C)[(size_t)(row + r) * N + col] = v;
                else        ((ushort*)C)[(size_t)(row + r) * N + col] = f2b(v);
            }
        }
    }
}

// Fused Q/K/Vt GEMM: 768 blocks (3/CU). RoPE fused (table) for Q,K jobs.
__global__ __launch_bounds__(256) void gemm_qkv(const ushort* __restrict__ xb,
                                                const ushort* __restrict__ wqb,
                                                const ushort* __restrict__ wkb,
                                                const ushort* __restrict__ wvb,
                                                ushort* __restrict__ q,
                                                ushort* __restrict__ k,
                                                ushort* __restrict__ vt,
                                                const float2* __restrict__ tab) {
    __shared__ __align__(16) ushort As[8192], Bs[8192];
    const int blk = blockIdx.x;
    const int job = blk >> 8, r = blk & 255;
    const ushort *A, *B;
    ushort* C;
    int N, m0, n0;
    bool rope;
    if (job == 0)      { A = xb;  B = wqb; C = q;  N = 1024; m0 = (r >> 3) * 128; n0 = (r & 7) * 128; rope = true; }
    else if (job == 1) { A = xb;  B = wkb; C = k;  N = 1024; m0 = (r >> 3) * 128; n0 = (r & 7) * 128; rope = true; }
    else               { A = wvb; B = xb;  C = vt; N = 4096; m0 = (r & 7) * 128;  n0 = (r >> 3) * 128; rope = false; }
    gemm_body<false>(As, Bs, A, B, C, N, m0, n0, rope, tab);
}

// Output projection: C fp32 = O[4096][1024] * wo[1024][1024]^T
__global__ __launch_bounds__(256) void gemm_o(const ushort* __restrict__ A,
                                              const ushort* __restrict__ B,
                                              float* __restrict__ C) {
    __shared__ __align__(16) ushort As[8192], Bs[8192];
    gemm_body<true>(As, Bs, A, B, C, 1024, blockIdx.y * 128, blockIdx.x * 128, false, nullptr);
}

// Causal flash attention. 512 blocks x 256 threads (4 waves; wave w = q-rows
// w*16..w*16+15 of a 64-row q-tile). Each block runs halves (qt=pr, 31-pr):
// exactly 33 k-tile iterations per block regardless of dispatch order.
// bh = blk&31 -> blk%8 = bh%8: all blocks of one bh stay on one XCD (L2 reuse).
// S^T = K Q^T (q=lane&15). FIXED-REFERENCE softmax: p = 2^(s*0.125*log2 e)
// (|s| <~ 8 << exp headroom; relative precision identical to max-tracking) --
// no running max, no alpha rescale, no serial dependency. P stays in regs.
__global__ __launch_bounds__(256) void attn_k(const ushort* __restrict__ Qg,
                                              const ushort* __restrict__ Kg,
                                              const ushort* __restrict__ Vtg,
                                              ushort* __restrict__ Og) {
    __shared__ __align__(16) ushort Ks[2][4096];   // [s][d] chunk-swizzled
    __shared__ __align__(16) ushort Vs[2][4096];   // [d][s] chunk-swizzled

    const int tid = threadIdx.x;
    const int wave = tid >> 6, lane = tid & 63;
    const int quad = lane >> 4, l16 = lane & 15;
    const int blk = blockIdx.x;
    const int bh = blk & 31, pr = blk >> 5;        // pr in 0..15
    const int b = bh >> 4, h = bh & 15;
    const int bq = b * 2048;
    const int wl = wave * 16 + l16;                // q-row within 64-row tile

    const int cA = tid, cB = tid + 256;
    const int sA = cA >> 3, jA = ((cA & 7) - sA) & 7;
    const int sB = cB >> 3, jB = ((cB & 7) - sB) & 7;
    const ushort* kgA = Kg + (size_t)(bq + sA) * 1024 + h * 64 + jA * 8;
    const ushort* kgB = Kg + (size_t)(bq + sB) * 1024 + h * 64 + jB * 8;
    const ushort* vgA = Vtg + (size_t)(h * 64 + sA) * 4096 + bq + jA * 8;
    const ushort* vgB = Vtg + (size_t)(h * 64 + sB) * 4096 + bq + jB * 8;

    const float SCL = 0.18033688011112042f;        // 0.125 * log2(e)

    for (int half = 0; half < 2; ++half) {
        const int qt = half ? (31 - pr) : pr;      // 64-row q-tile index
        const int nk = qt + 1;
        const int dt = nk - 1;

        const ushort* qrow = Qg + (size_t)(bq + qt * 64 + wl) * 1024 + h * 64 + quad * 8;
        const short8 qf0 = *(const short8*)qrow;
        const short8 qf1 = *(const short8*)(qrow + 32);

        floatx4 od[4] = {};
        float l_st = 0.0f;

        load_lds16(kgA, &Ks[0][cA * 8]);
        load_lds16(kgB, &Ks[0][cB * 8]);
        load_lds16(vgA, &Vs[0][cA * 8]);
        load_lds16(vgB, &Vs[0][cB * 8]);
        __syncthreads();

        for (int kt = 0; kt < nk; ++kt) {
            const int cur = kt & 1;
            if (kt + 1 < nk) {
                const int nxt = cur ^ 1;
                load_lds16(kgA + (size_t)(kt + 1) * 65536, &Ks[nxt][cA * 8]);
                load_lds16(kgB + (size_t)(kt + 1) * 65536, &Ks[nxt][cB * 8]);
                load_lds16(vgA + (kt + 1) * 64, &Vs[nxt][cA * 8]);
                load_lds16(vgB + (kt + 1) * 64, &Vs[nxt][cB * 8]);
            }
            const ushort* kb = Ks[cur];
            const ushort* vb = Vs[cur];

            // S^T = K Q^T
            floatx4 st[4];
#pragma unroll
            for (int cb = 0; cb < 4; ++cb) {
                const int s = cb * 16 + l16;
                const int ch0 = s * 8 + ((quad + s) & 7);
                const int ch1 = s * 8 + ((quad + 4 + s) & 7);
                short8 kf0 = *(const short8*)(kb + ch0 * 8);
                short8 kf1 = *(const short8*)(kb + ch1 * 8);
                floatx4 z = {};
                z = __builtin_amdgcn_mfma_f32_16x16x32_bf16(kf0, qf0, z, 0, 0, 0);
                z = __builtin_amdgcn_mfma_f32_16x16x32_bf16(kf1, qf1, z, 0, 0, 0);
                st[cb] = z;
            }

            // fixed-reference softmax: p = 2^(s*SCL), causal-masked to 0
            const bool diag = (kt == dt);
            float pv[4][4];
            float sum = 0.0f;
#pragma unroll
            for (int cb = 0; cb < 4; ++cb) {
                const int scb = cb * 16 + quad * 4;
#pragma unroll
                for (int r = 0; r < 4; ++r) {
                    float e = exp2f(st[cb][r] * SCL);
                    if (diag && (scb + r > wl)) e = 0.0f;
                    pv[cb][r] = e;
                    sum += e;
                }
            }
            sum += __shfl_xor(sum, 16);
            sum += __shfl_xor(sum, 32);
            l_st += sum;

            // P^T fragments (B-operand of 16x16x16) straight from registers
            short4v pb[4];
#pragma unroll
            for (int cb = 0; cb < 4; ++cb) {
                short4v pk;
#pragma unroll
                for (int r = 0; r < 4; ++r) pk[r] = (short)f2b_fast(pv[cb][r]);
                pb[cb] = pk;
            }
            // O^T += V^T P^T (no rescale needed)
#pragma unroll
            for (int db = 0; db < 4; ++db) {
                const int d = db * 16 + l16;
#pragma unroll
                for (int cb = 0; cb < 4; ++cb) {
                    const int j = cb * 2 + (quad >> 1);
                    const int ch = d * 8 + ((j + d) & 7);
                    short4v vf = *(const short4v*)(vb + ch * 8 + (quad & 1) * 4);
                    od[db] = __builtin_amdgcn_mfma_f32_16x16x16bf16_1k(vf, pb[cb], od[db], 0, 0, 0);
                }
            }
            __syncthreads();   // cur reads done + prefetch drained
        }

        const float linv = 1.0f / l_st;
        ushort* orow = Og + (size_t)(bq + qt * 64 + wl) * 1024 + h * 64 + quad * 4;
#pragma unroll
        for (int db = 0; db < 4; ++db) {
            uint2 w;
            w.x = (uint)f2b(od[db][0] * linv) | ((uint)f2b(od[db][1] * linv) << 16);
            w.y = (uint)f2b(od[db][2] * linv) | ((uint)f2b(od[db][3] * linv) << 16);
            *(uint2*)(orow + db * 16) = w;
        }
    }
}

extern "C" void kernel_launch(void* const* d_in, const int* in_sizes, int n_in,
                              void* d_out, int out_size, void* d_ws, size_t ws_size,
                              hipStream_t stream) {
    const float* x  = (const float*)d_in[0];
    const float* wq = (const float*)d_in[1];
    const float* wk = (const float*)d_in[2];
    const float* wv = (const float*)d_in[3];
    const float* wo = (const float*)d_in[4];
    const int* pos  = (const int*)d_in[5];

    const size_t NX = (size_t)4096 * 1024;
    const size_t NW = (size_t)1024 * 1024;

    ushort* q_ws  = (ushort*)d_ws;          // 8 MB each, 32 MiB total
    ushort* k_ws  = q_ws + NX;
    ushort* vt_ws = k_ws + NX;
    ushort* o_ws  = vt_ws + NX;
    // d_out (16 MB) doubles as bf16 scratch + rope table until the final GEMM
    ushort* xb  = (ushort*)d_out;           // 8 MB
    ushort* wqb = xb + NX;                  // 2 MB each
    ushort* wkb = wqb + NW;
    ushort* wvb = wkb + NW;
    float2* tab = (float2*)(wvb + NW);      // 512 KB

    rope_tab_k<<<dim3(256), 256, 0, stream>>>(pos, tab);
    cvt4_k<<<dim3(3584), 256, 0, stream>>>(x, wq, wk, wv, xb, wqb, wkb, wvb);
    gemm_qkv<<<dim3(768), 256, 0, stream>>>(xb, wqb, wkb, wvb, q_ws, k_ws, vt_ws, tab);
    attn_k<<<dim3(512), 256, 0, stream>>>(q_ws, k_ws, vt_ws, o_ws);
    cvt_k<<<dim3(512), 256, 0, stream>>>(wo, q_ws, (int)NW);   // q_ws dead now
    gemm_o<<<dim3(8, 32), 256, 0, stream>>>(o_ws, q_ws, (float*)d_out);
}

// Round 9
// 204.442 us; speedup vs baseline: 1.2361x; 1.0502x over previous
//
#include <hip/hip_runtime.h>

typedef __attribute__((ext_vector_type(8))) short short8;
typedef __attribute__((ext_vector_type(4))) short short4v;
typedef __attribute__((ext_vector_type(4))) float floatx4;

__device__ inline float b2f(ushort u) {
    union { uint i; float f; } c; c.i = ((uint)u) << 16; return c.f;
}
__device__ inline ushort f2b(float f) {
    union { uint i; float f; } c; c.f = f;
    uint i = c.i;
    uint r = (i + 0x7FFFu + ((i >> 16) & 1u)) >> 16;
    return (ushort)r;
}
__device__ inline ushort f2b_fast(float f) {   // round-half-up; fine for P >= 0
    union { uint i; float f; } c; c.f = f;
    return (ushort)((c.i + 0x8000u) >> 16);
}

__device__ __forceinline__ void load_lds16(const ushort* g, ushort* l) {
    __builtin_amdgcn_global_load_lds((const __attribute__((address_space(1))) void*)g,
                                     (__attribute__((address_space(3))) void*)l, 16, 0, 0);
}

// RoPE cos/sin table: tab[s][fi] = {cos, sin}(pos[s] * theta^(-fi/32)), 2048x32.
__global__ __launch_bounds__(256) void rope_tab_k(const int* __restrict__ pos,
                                                  float2* __restrict__ tab) {
    const int idx = blockIdx.x * 256 + threadIdx.x;   // 0..65535
    const int s = idx >> 5, fi = idx & 31;
    const float inv = exp2f(-(float)fi * 0.41524101186092557f);
    const float ang = (float)pos[s] * inv;
    float sn, cs;
    sincosf(ang, &sn, &cs);
    tab[idx] = make_float2(cs, sn);
}

// Fused fp32->bf16 conversion of x, wq, wk, wv (one launch).
__global__ __launch_bounds__(256) void cvt4_k(const float* __restrict__ x,
                                              const float* __restrict__ wq,
                                              const float* __restrict__ wk,
                                              const float* __restrict__ wv,
                                              ushort* __restrict__ xb,
                                              ushort* __restrict__ wqb,
                                              ushort* __restrict__ wkb,
                                              ushort* __restrict__ wvb) {
    const int blk = blockIdx.x;
    const float* in; ushort* out; int base;
    if (blk < 2048)      { in = x;  out = xb;  base = blk; }
    else if (blk < 2560) { in = wq; out = wqb; base = blk - 2048; }
    else if (blk < 3072) { in = wk; out = wkb; base = blk - 2560; }
    else                 { in = wv; out = wvb; base = blk - 3072; }
    const int i = (base * 256 + threadIdx.x) * 8;
    float4 f0 = *(const float4*)(in + i);
    float4 f1 = *(const float4*)(in + i + 4);
    ushort u[8] = {f2b(f0.x), f2b(f0.y), f2b(f0.z), f2b(f0.w),
                   f2b(f1.x), f2b(f1.y), f2b(f1.z), f2b(f1.w)};
    *(uint4*)(out + i) = *(const uint4*)u;
}

__global__ __launch_bounds__(256) void cvt_k(const float* __restrict__ in,
                                             ushort* __restrict__ out, int n) {
    const int i = (blockIdx.x * 256 + threadIdx.x) * 8;
    if (i >= n) return;
    float4 f0 = *(const float4*)(in + i);
    float4 f1 = *(const float4*)(in + i + 4);
    ushort u[8] = {f2b(f0.x), f2b(f0.y), f2b(f0.z), f2b(f0.w),
                   f2b(f1.x), f2b(f1.y), f2b(f1.z), f2b(f1.w)};
    *(uint4*)(out + i) = *(const uint4*)u;
}

// 128x128 GEMM body, K=1024, BK=32, 4 waves (2x2 of 64x64).
// DOUBLE-BUFFERED LDS, ONE barrier per K-iter: prefetch tile kt+1 into the
// other buffer, compute tile kt, sync. Staging overlaps compute (attn_k shape).
// LDS tile = 128 rows x 32 cols (8 KB); chunk swizzle j_lds = (j_g + (row>>1))&3
// packs wave64 ds_read_b128 into the dense 8-phase minimum (2 lanes/bank, free).
// Optional fused RoPE epilogue via precomputed table.
template <bool OUTF32>
__device__ __forceinline__ void gemm_body(ushort* As, ushort* Bs,   // [2][4096] each
                                          const ushort* __restrict__ A,
                                          const ushort* __restrict__ B,
                                          void* __restrict__ C,
                                          int N, int m0, int n0,
                                          bool doRope, const float2* __restrict__ tab) {
    const int tid = threadIdx.x;
    const int wave = tid >> 6, lane = tid & 63;
    const int quad = lane >> 4, l16 = lane & 15;
    const int wm = (wave >> 1) * 64, wn = (wave & 1) * 64;

    floatx4 acc[4][4] = {};

    // staging: 512 chunks (16B) per tile; thread covers cA=tid, cB=tid+256
    const int cA = tid, cB = tid + 256;
    const int rA = cA >> 2, jgA = ((cA & 3) - (rA >> 1)) & 3;
    const int rB = cB >> 2, jgB = ((cB & 3) - (rB >> 1)) & 3;
    const ushort* gaA = A + (size_t)(m0 + rA) * 1024 + jgA * 8;
    const ushort* gaB = A + (size_t)(m0 + rB) * 1024 + jgB * 8;
    const ushort* gbA = B + (size_t)(n0 + rA) * 1024 + jgA * 8;
    const ushort* gbB = B + (size_t)(n0 + rB) * 1024 + jgB * 8;

    // prologue: stage k-tile 0 into buffer 0
    load_lds16(gaA, As + cA * 8);
    load_lds16(gaB, As + cB * 8);
    load_lds16(gbA, Bs + cA * 8);
    load_lds16(gbB, Bs + cB * 8);
    __syncthreads();

    for (int kt = 0; kt < 32; ++kt) {
        const int cur = kt & 1;
        if (kt + 1 < 32) {                       // prefetch next tile
            const int nb = (cur ^ 1) * 4096;
            load_lds16(gaA + (kt + 1) * 32, As + nb + cA * 8);
            load_lds16(gaB + (kt + 1) * 32, As + nb + cB * 8);
            load_lds16(gbA + (kt + 1) * 32, Bs + nb + cA * 8);
            load_lds16(gbB + (kt + 1) * 32, Bs + nb + cB * 8);
        }
        const ushort* as = As + cur * 4096;
        const ushort* bs = Bs + cur * 4096;
        short8 af[4], bf[4];
#pragma unroll
        for (int i = 0; i < 4; ++i) {
            const int ra = wm + i * 16 + l16;
            const int rb = wn + i * 16 + l16;
            af[i] = *(const short8*)(as + ra * 32 + (((quad + (ra >> 1)) & 3) << 3));
            bf[i] = *(const short8*)(bs + rb * 32 + (((quad + (rb >> 1)) & 3) << 3));
        }
#pragma unroll
        for (int mi = 0; mi < 4; ++mi)
#pragma unroll
            for (int ni = 0; ni < 4; ++ni)
                acc[mi][ni] = __builtin_amdgcn_mfma_f32_16x16x32_bf16(af[mi], bf[ni], acc[mi][ni], 0, 0, 0);
        __syncthreads();                         // cur reads done + prefetch drained
    }
#pragma unroll
    for (int mi = 0; mi < 4; ++mi) {
        const int row = m0 + wm + mi * 16 + quad * 4;
#pragma unroll
        for (int ni = 0; ni < 4; ++ni) {
            const int col = n0 + wn + ni * 16 + l16;
            const int fi = ((wn + ni * 16 + l16) & 63) >> 1;
#pragma unroll
            for (int r = 0; r < 4; ++r) {
                float v = acc[mi][ni][r];
                if (doRope) {
                    const float other = __shfl_xor(v, 1);
                    const float2 cs = tab[((row + r) & 2047) * 32 + fi];
                    v = (col & 1) ? (other * cs.y + v * cs.x) : (v * cs.x - other * cs.y);
                }
                if (OUTF32) ((float*)C)[(size_t)(row + r) * N + col] = v;
                else        ((ushort*)C)[(size_t)(row + r) * N + col] = f2b(v);
            }
        }
    }
}

// Fused Q/K/Vt GEMM: 768 blocks (3/CU). RoPE fused (table) for Q,K jobs.
__global__ __launch_bounds__(256) void gemm_qkv(const ushort* __restrict__ xb,
                                                const ushort* __restrict__ wqb,
                                                const ushort* __restrict__ wkb,
                                                const ushort* __restrict__ wvb,
                                                ushort* __restrict__ q,
                                                ushort* __restrict__ k,
                                                ushort* __restrict__ vt,
                                                const float2* __restrict__ tab) {
    __shared__ __align__(16) ushort As[8192], Bs[8192];   // 2 bufs x 8 KB each
    const int blk = blockIdx.x;
    const int job = blk >> 8, r = blk & 255;
    const ushort *A, *B;
    ushort* C;
    int N, m0, n0;
    bool rope;
    if (job == 0)      { A = xb;  B = wqb; C = q;  N = 1024; m0 = (r >> 3) * 128; n0 = (r & 7) * 128; rope = true; }
    else if (job == 1) { A = xb;  B = wkb; C = k;  N = 1024; m0 = (r >> 3) * 128; n0 = (r & 7) * 128; rope = true; }
    else               { A = wvb; B = xb;  C = vt; N = 4096; m0 = (r & 7) * 128;  n0 = (r >> 3) * 128; rope = false; }
    gemm_body<false>(As, Bs, A, B, C, N, m0, n0, rope, tab);
}

// Output projection: C fp32 = O[4096][1024] * wo[1024][1024]^T
__global__ __launch_bounds__(256) void gemm_o(const ushort* __restrict__ A,
                                              const ushort* __restrict__ B,
                                              float* __restrict__ C) {
    __shared__ __align__(16) ushort As[8192], Bs[8192];
    gemm_body<true>(As, Bs, A, B, C, 1024, blockIdx.y * 128, blockIdx.x * 128, false, nullptr);
}

// Causal flash attention (unchanged from round 8 — verified).
__global__ __launch_bounds__(256) void attn_k(const ushort* __restrict__ Qg,
                                              const ushort* __restrict__ Kg,
                                              const ushort* __restrict__ Vtg,
                                              ushort* __restrict__ Og) {
    __shared__ __align__(16) ushort Ks[2][4096];   // [s][d] chunk-swizzled
    __shared__ __align__(16) ushort Vs[2][4096];   // [d][s] chunk-swizzled

    const int tid = threadIdx.x;
    const int wave = tid >> 6, lane = tid & 63;
    const int quad = lane >> 4, l16 = lane & 15;
    const int blk = blockIdx.x;
    const int bh = blk & 31, pr = blk >> 5;        // pr in 0..15
    const int b = bh >> 4, h = bh & 15;
    const int bq = b * 2048;
    const int wl = wave * 16 + l16;                // q-row within 64-row tile

    const int cA = tid, cB = tid + 256;
    const int sA = cA >> 3, jA = ((cA & 7) - sA) & 7;
    const int sB = cB >> 3, jB = ((cB & 7) - sB) & 7;
    const ushort* kgA = Kg + (size_t)(bq + sA) * 1024 + h * 64 + jA * 8;
    const ushort* kgB = Kg + (size_t)(bq + sB) * 1024 + h * 64 + jB * 8;
    const ushort* vgA = Vtg + (size_t)(h * 64 + sA) * 4096 + bq + jA * 8;
    const ushort* vgB = Vtg + (size_t)(h * 64 + sB) * 4096 + bq + jB * 8;

    const float SCL = 0.18033688011112042f;        // 0.125 * log2(e)

    for (int half = 0; half < 2; ++half) {
        const int qt = half ? (31 - pr) : pr;      // 64-row q-tile index
        const int nk = qt + 1;
        const int dt = nk - 1;

        const ushort* qrow = Qg + (size_t)(bq + qt * 64 + wl) * 1024 + h * 64 + quad * 8;
        const short8 qf0 = *(const short8*)qrow;
        const short8 qf1 = *(const short8*)(qrow + 32);

        floatx4 od[4] = {};
        float l_st = 0.0f;

        load_lds16(kgA, &Ks[0][cA * 8]);
        load_lds16(kgB, &Ks[0][cB * 8]);
        load_lds16(vgA, &Vs[0][cA * 8]);
        load_lds16(vgB, &Vs[0][cB * 8]);
        __syncthreads();

        for (int kt = 0; kt < nk; ++kt) {
            const int cur = kt & 1;
            if (kt + 1 < nk) {
                const int nxt = cur ^ 1;
                load_lds16(kgA + (size_t)(kt + 1) * 65536, &Ks[nxt][cA * 8]);
                load_lds16(kgB + (size_t)(kt + 1) * 65536, &Ks[nxt][cB * 8]);
                load_lds16(vgA + (kt + 1) * 64, &Vs[nxt][cA * 8]);
                load_lds16(vgB + (kt + 1) * 64, &Vs[nxt][cB * 8]);
            }
            const ushort* kb = Ks[cur];
            const ushort* vb = Vs[cur];

            // S^T = K Q^T
            floatx4 st[4];
#pragma unroll
            for (int cb = 0; cb < 4; ++cb) {
                const int s = cb * 16 + l16;
                const int ch0 = s * 8 + ((quad + s) & 7);
                const int ch1 = s * 8 + ((quad + 4 + s) & 7);
                short8 kf0 = *(const short8*)(kb + ch0 * 8);
                short8 kf1 = *(const short8*)(kb + ch1 * 8);
                floatx4 z = {};
                z = __builtin_amdgcn_mfma_f32_16x16x32_bf16(kf0, qf0, z, 0, 0, 0);
                z = __builtin_amdgcn_mfma_f32_16x16x32_bf16(kf1, qf1, z, 0, 0, 0);
                st[cb] = z;
            }

            // fixed-reference softmax: p = 2^(s*SCL), causal-masked to 0
            const bool diag = (kt == dt);
            float pv[4][4];
            float sum = 0.0f;
#pragma unroll
            for (int cb = 0; cb < 4; ++cb) {
                const int scb = cb * 16 + quad * 4;
#pragma unroll
                for (int r = 0; r < 4; ++r) {
                    float e = exp2f(st[cb][r] * SCL);
                    if (diag && (scb + r > wl)) e = 0.0f;
                    pv[cb][r] = e;
                    sum += e;
                }
            }
            sum += __shfl_xor(sum, 16);
            sum += __shfl_xor(sum, 32);
            l_st += sum;

            // P^T fragments (B-operand of 16x16x16) straight from registers
            short4v pb[4];
#pragma unroll
            for (int cb = 0; cb < 4; ++cb) {
                short4v pk;
#pragma unroll
                for (int r = 0; r < 4; ++r) pk[r] = (short)f2b_fast(pv[cb][r]);
                pb[cb] = pk;
            }
            // O^T += V^T P^T (no rescale needed)
#pragma unroll
            for (int db = 0; db < 4; ++db) {
                const int d = db * 16 + l16;
#pragma unroll
                for (int cb = 0; cb < 4; ++cb) {
                    const int j = cb * 2 + (quad >> 1);
                    const int ch = d * 8 + ((j + d) & 7);
                    short4v vf = *(const short4v*)(vb + ch * 8 + (quad & 1) * 4);
                    od[db] = __builtin_amdgcn_mfma_f32_16x16x16bf16_1k(vf, pb[cb], od[db], 0, 0, 0);
                }
            }
            __syncthreads();   // cur reads done + prefetch drained
        }

        const float linv = 1.0f / l_st;
        ushort* orow = Og + (size_t)(bq + qt * 64 + wl) * 1024 + h * 64 + quad * 4;
#pragma unroll
        for (int db = 0; db < 4; ++db) {
            uint2 w;
            w.x = (uint)f2b(od[db][0] * linv) | ((uint)f2b(od[db][1] * linv) << 16);
            w.y = (uint)f2b(od[db][2] * linv) | ((uint)f2b(od[db][3] * linv) << 16);
            *(uint2*)(orow + db * 16) = w;
        }
    }
}

extern "C" void kernel_launch(void* const* d_in, const int* in_sizes, int n_in,
                              void* d_out, int out_size, void* d_ws, size_t ws_size,
                              hipStream_t stream) {
    const float* x  = (const float*)d_in[0];
    const float* wq = (const float*)d_in[1];
    const float* wk = (const float*)d_in[2];
    const float* wv = (const float*)d_in[3];
    const float* wo = (const float*)d_in[4];
    const int* pos  = (const int*)d_in[5];

    const size_t NX = (size_t)4096 * 1024;
    const size_t NW = (size_t)1024 * 1024;

    ushort* q_ws  = (ushort*)d_ws;          // 8 MB each, 32 MiB total
    ushort* k_ws  = q_ws + NX;
    ushort* vt_ws = k_ws + NX;
    ushort* o_ws  = vt_ws + NX;
    // d_out (16 MB) doubles as bf16 scratch + rope table until the final GEMM
    ushort* xb  = (ushort*)d_out;           // 8 MB
    ushort* wqb = xb + NX;                  // 2 MB each
    ushort* wkb = wqb + NW;
    ushort* wvb = wkb + NW;
    float2* tab = (float2*)(wvb + NW);      // 512 KB

    rope_tab_k<<<dim3(256), 256, 0, stream>>>(pos, tab);
    cvt4_k<<<dim3(3584), 256, 0, stream>>>(x, wq, wk, wv, xb, wqb, wkb, wvb);
    gemm_qkv<<<dim3(768), 256, 0, stream>>>(xb, wqb, wkb, wvb, q_ws, k_ws, vt_ws, tab);
    attn_k<<<dim3(512), 256, 0, stream>>>(q_ws, k_ws, vt_ws, o_ws);
    cvt_k<<<dim3(512), 256, 0, stream>>>(wo, q_ws, (int)NW);   // q_ws dead now
    gemm_o<<<dim3(8, 32), 256, 0, stream>>>(o_ws, q_ws, (float*)d_out);
}